// Round 1
// baseline (826.148 us; speedup 1.0000x reference)
//
#include <hip/hip_runtime.h>
#include <hip/hip_fp16.h>

// Problem constants
#define Bc  64
#define Sc  256
#define Icc 256
#define Hh  512
#define HW  1024   // 2*Hh

__device__ __forceinline__ float fast_tanh(float x) {
  // tanh(x) = 1 - 2/(e^{2x}+1); exact at +-inf, ~1e-6 abs error
  float e = __expf(2.0f * x);
  return 1.0f - 2.0f * __builtin_amdgcn_rcpf(e + 1.0f);
}

template <typename T>
__device__ __forceinline__ float ldf(const T* p) {
  if constexpr (sizeof(T) == 4) return *p;
  else return __half2float(*p);
}
template <typename T>
__device__ __forceinline__ void stf(T* p, float v) {
  if constexpr (sizeof(T) == 4) *p = v;
  else *p = __float2half(v);
}

// ---------------- GEMM: I[m][h] = sum_k X[m][k] * W[h][k] ----------------
// M=16384, N=1024, K=256. 64x64 tile, 256 threads, 4x4 per thread.
template <typename T>
__global__ __launch_bounds__(256) void gemm_xw(const float* __restrict__ X,
                                               const float* __restrict__ Wm,
                                               T* __restrict__ Out) {
  __shared__ float As[16][68];  // [k][m], pad keeps 16B alignment, 2-way max
  __shared__ float Bs[16][68];  // [k][n]
  const int tid = threadIdx.x;
  const int m0 = blockIdx.x << 6;
  const int n0 = blockIdx.y << 6;
  const int tx = tid & 15;   // n quad
  const int ty = tid >> 4;   // m quad
  const int lr = tid >> 2;   // 0..63 load row
  const int lk = (tid & 3) << 2;

  float acc[4][4];
#pragma unroll
  for (int i = 0; i < 4; ++i)
#pragma unroll
    for (int j = 0; j < 4; ++j) acc[i][j] = 0.0f;

  const float* xg = X + (size_t)(m0 + lr) * Icc + lk;
  const float* wg = Wm + (size_t)(n0 + lr) * Icc + lk;

  for (int k0 = 0; k0 < Icc; k0 += 16) {
    float4 av = *(const float4*)(xg + k0);
    float4 bv = *(const float4*)(wg + k0);
    __syncthreads();  // protect previous iter's LDS reads
    As[lk + 0][lr] = av.x; As[lk + 1][lr] = av.y;
    As[lk + 2][lr] = av.z; As[lk + 3][lr] = av.w;
    Bs[lk + 0][lr] = bv.x; Bs[lk + 1][lr] = bv.y;
    Bs[lk + 2][lr] = bv.z; Bs[lk + 3][lr] = bv.w;
    __syncthreads();
#pragma unroll
    for (int kk = 0; kk < 16; ++kk) {
      float a[4], b[4];
      *(float4*)a = *(const float4*)&As[kk][ty << 2];
      *(float4*)b = *(const float4*)&Bs[kk][tx << 2];
#pragma unroll
      for (int i = 0; i < 4; ++i)
#pragma unroll
        for (int j = 0; j < 4; ++j) acc[i][j] += a[i] * b[j];
    }
  }
#pragma unroll
  for (int i = 0; i < 4; ++i) {
    T* op = Out + (size_t)(m0 + (ty << 2) + i) * HW + n0 + (tx << 2);
    if constexpr (sizeof(T) == 4) {
      *(float4*)op = make_float4(acc[i][0], acc[i][1], acc[i][2], acc[i][3]);
    } else {
#pragma unroll
      for (int j = 0; j < 4; ++j) stf(op + j, acc[i][j]);
    }
  }
}

// ---------------- Scan: mem resident in registers ----------------
// Grid (8, 64): blockIdx.y = batch, blockIdx.x = row-block (64 rows).
// 256 threads: row r = tid&63, col chunk = tid>>6 (128 cols). mem: 128 VGPRs.
template <typename T>
__global__ __launch_bounds__(256, 2) void scan_kernel(const T* __restrict__ If,
                                                      float* __restrict__ mem_out,
                                                      float* __restrict__ keys,
                                                      float* __restrict__ vals) {
  const int b = blockIdx.y;
  const int rb = blockIdx.x;
  const int tid = threadIdx.x;
  const int wave = tid >> 6;
  const int r = tid & 63;
  const int r0 = rb << 6;

  __shared__ float k_s[2][512];   // double-buffered: saves a 4th barrier
  __shared__ float kt_s[2][512];
  __shared__ float red_s[4][64];
  __shared__ float a_s[64];
  __shared__ float c_s[64];

  constexpr float ALPHA = 0.90483741803595957f;  // exp(-1/10)
  constexpr float DT    = 0.95122942450071400f;  // exp(-1/20)
  constexpr float OMD   = 0.04877057549928599f;  // 1 - DT
  constexpr float LR_   = 0.01f;

  float memreg[128];
#pragma unroll
  for (int j = 0; j < 128; ++j) memreg[j] = 0.0f;
  float ks0 = 0.f, ks1 = 0.f, kt0 = 0.f, kt1 = 0.f, vs = 0.f, vt = 0.f;

  const T* ibase = If + (size_t)b * Sc * HW;
  float* keysb = keys + (size_t)b * Sc * Hh;
  float* valsb = vals + (size_t)b * Sc * Hh;

  for (int t = 0; t < Sc; ++t) {
    const T* row = ibase + (size_t)t * HW;
    // phase 1: elementwise k recurrence (full 512, redundant per row-block)
    float ik0 = ldf(row + tid);
    float ik1 = ldf(row + tid + 256);
    float ivr = 0.0f;
    if (wave == 0) ivr = ldf(row + 512 + r0 + r);
    ks0 = ALPHA * ks0 + ik0;
    ks1 = ALPHA * ks1 + ik1;
    float k0 = fast_tanh(ks0);
    float k1 = fast_tanh(ks1);
    kt0 = DT * kt0 + OMD * k0;
    kt1 = DT * kt1 + OMD * k1;
    const int buf = t & 1;
    k_s[buf][tid] = k0;   k_s[buf][tid + 256] = k1;
    kt_s[buf][tid] = kt0; kt_s[buf][tid + 256] = kt1;
    if (rb == 0) {
      keysb[t * Hh + tid] = k0;
      keysb[t * Hh + tid + 256] = k1;
    }
    __syncthreads();  // B1: k_s/kt_s ready

    // phase 2: matvec partial ikv[r] over this thread's 128 cols (old mem, new k)
    {
      const float4* kc4 = (const float4*)&k_s[buf][wave << 7];
      float p0 = 0.f, p1 = 0.f, p2 = 0.f, p3 = 0.f;
#pragma unroll
      for (int j4 = 0; j4 < 32; ++j4) {
        float4 kv = kc4[j4];  // whole-wave broadcast, conflict-free
        p0 += memreg[4 * j4 + 0] * kv.x;
        p1 += memreg[4 * j4 + 1] * kv.y;
        p2 += memreg[4 * j4 + 2] * kv.z;
        p3 += memreg[4 * j4 + 3] * kv.w;
      }
      red_s[wave][r] = (p0 + p1) + (p2 + p3);
    }
    __syncthreads();  // B2: partials ready

    // phase 3: wave 0 owns the v recurrence for this block's 64 rows
    if (wave == 0) {
      float ikv = 0.2f * ((red_s[0][r] + red_s[1][r]) + (red_s[2][r] + red_s[3][r]));
      vs = ALPHA * vs + ivr + ikv;
      float v = fast_tanh(vs);
      vt = DT * vt + OMD * v;
      valsb[t * Hh + r0 + r] = v;
      a_s[r] = 1.0f - LR_ * vt * vt;  // row decay
      c_s[r] = LR_ * vt;              // row gain on kt
    }
    __syncthreads();  // B3: a_s/c_s ready

    // phase 4: rank-1 mem update (new kt, new vt)
    {
      const float ar = a_s[r];
      const float cr = c_s[r];
      const float4* kt4 = (const float4*)&kt_s[buf][wave << 7];
#pragma unroll
      for (int j4 = 0; j4 < 32; ++j4) {
        float4 kv = kt4[j4];
        memreg[4 * j4 + 0] = memreg[4 * j4 + 0] * ar + cr * kv.x;
        memreg[4 * j4 + 1] = memreg[4 * j4 + 1] * ar + cr * kv.y;
        memreg[4 * j4 + 2] = memreg[4 * j4 + 2] * ar + cr * kv.z;
        memreg[4 * j4 + 3] = memreg[4 * j4 + 3] * ar + cr * kv.w;
      }
    }
  }

  // epilogue: write mem (once)
  float* mb = mem_out + (size_t)b * Hh * Hh + (size_t)(r0 + r) * Hh + (wave << 7);
#pragma unroll
  for (int j = 0; j < 128; j += 4) {
    *(float4*)(mb + j) =
        make_float4(memreg[j], memreg[j + 1], memreg[j + 2], memreg[j + 3]);
  }
}

extern "C" void kernel_launch(void* const* d_in, const int* in_sizes, int n_in,
                              void* d_out, int out_size, void* d_ws, size_t ws_size,
                              hipStream_t stream) {
  const float* x = (const float*)d_in[0];   // (64,256,256) fp32
  const float* W = (const float*)d_in[1];   // (1024,256) fp32
  float* out = (float*)d_out;
  float* mem_out = out;                          // 16,777,216 floats
  float* keys    = out + 16777216;               //  8,388,608 floats
  float* vals    = out + 25165824;               //  8,388,608 floats

  const dim3 gemm_grid(256, 16), gemm_blk(256);
  const dim3 scan_grid(8, 64),  scan_blk(256);
  const size_t i_elems = (size_t)Bc * Sc * HW;   // 16,777,216

  if (ws_size >= i_elems * sizeof(float)) {
    float* If = (float*)d_ws;
    gemm_xw<float><<<gemm_grid, gemm_blk, 0, stream>>>(x, W, If);
    scan_kernel<float><<<scan_grid, scan_blk, 0, stream>>>(If, mem_out, keys, vals);
  } else {
    // fp16 staging fallback (abs err on i ~1e-3, amplified ~x10 by the ks
    // recurrence -> still well under the 2e-2 threshold)
    __half* If = (__half*)d_ws;
    gemm_xw<__half><<<gemm_grid, gemm_blk, 0, stream>>>(x, W, If);
    scan_kernel<__half><<<scan_grid, scan_blk, 0, stream>>>(If, mem_out, keys, vals);
  }
}

// Round 2
// 740.318 us; speedup vs baseline: 1.1159x; 1.1159x over previous
//
#include <hip/hip_runtime.h>
#include <hip/hip_fp16.h>

// Problem constants
#define Bc  64
#define Sc  256
#define Icc 256
#define Hh  512
#define HW  1024   // 2*Hh

// swizzle: insert 4 floats of pad per 16 so the 8 col-chunk broadcast b128
// reads per wave hit disjoint 4-bank groups (ch*20 % 32 all distinct)
#define SWZ(h) ((h) + (((h) >> 4) << 2))

__device__ __forceinline__ float fast_tanh(float x) {
  float e = __expf(2.0f * x);
  return 1.0f - 2.0f * __builtin_amdgcn_rcpf(e + 1.0f);
}

template <typename T>
__device__ __forceinline__ float ldf(const T* p) {
  if constexpr (sizeof(T) == 4) return *p;
  else return __half2float(*p);
}
template <typename T>
__device__ __forceinline__ void stf(T* p, float v) {
  if constexpr (sizeof(T) == 4) *p = v;
  else *p = __float2half(v);
}

// ---------------- GEMM: I[m][h] = sum_k X[m][k] * W[h][k] ----------------
// M=16384, N=1024, K=256. 128x64 tile, 256 threads, 8x4 per thread.
template <typename T>
__global__ __launch_bounds__(256, 2) void gemm_xw(const float* __restrict__ X,
                                                  const float* __restrict__ Wm,
                                                  T* __restrict__ Out) {
  __shared__ float As[16][132];  // [k][m], pad 4
  __shared__ float Bs[16][68];   // [k][n], pad 4
  const int tid = threadIdx.x;
  const int m0 = blockIdx.x << 7;   // 128-tile
  const int n0 = blockIdx.y << 6;   // 64-tile
  const int tx4 = (tid & 15) << 2;  // n quad base
  const int ty4 = (tid >> 4) << 2;  // m quad base (0..60)
  const int lr = tid >> 2;          // 0..63 load row
  const int lk = (tid & 3) << 2;    // k quad

  float acc[8][4];
#pragma unroll
  for (int i = 0; i < 8; ++i)
#pragma unroll
    for (int j = 0; j < 4; ++j) acc[i][j] = 0.0f;

  const float* xg0 = X + (size_t)(m0 + lr) * Icc + lk;
  const float* xg1 = X + (size_t)(m0 + 64 + lr) * Icc + lk;
  const float* wg  = Wm + (size_t)(n0 + lr) * Icc + lk;

  for (int k0 = 0; k0 < Icc; k0 += 16) {
    float4 a0 = *(const float4*)(xg0 + k0);
    float4 a1 = *(const float4*)(xg1 + k0);
    float4 bv = *(const float4*)(wg + k0);
    __syncthreads();  // protect previous iter's LDS reads
    As[lk + 0][lr] = a0.x; As[lk + 1][lr] = a0.y;
    As[lk + 2][lr] = a0.z; As[lk + 3][lr] = a0.w;
    As[lk + 0][lr + 64] = a1.x; As[lk + 1][lr + 64] = a1.y;
    As[lk + 2][lr + 64] = a1.z; As[lk + 3][lr + 64] = a1.w;
    Bs[lk + 0][lr] = bv.x; Bs[lk + 1][lr] = bv.y;
    Bs[lk + 2][lr] = bv.z; Bs[lk + 3][lr] = bv.w;
    __syncthreads();
#pragma unroll
    for (int kk = 0; kk < 16; ++kk) {
      float a[8], b[4];
      *(float4*)&a[0] = *(const float4*)&As[kk][ty4];
      *(float4*)&a[4] = *(const float4*)&As[kk][ty4 + 64];
      *(float4*)&b[0] = *(const float4*)&Bs[kk][tx4];
#pragma unroll
      for (int i = 0; i < 8; ++i)
#pragma unroll
        for (int j = 0; j < 4; ++j) acc[i][j] = fmaf(a[i], b[j], acc[i][j]);
    }
  }
#pragma unroll
  for (int i = 0; i < 8; ++i) {
    const int mrow = m0 + ((i < 4) ? (ty4 + i) : (64 + ty4 + i - 4));
    T* op = Out + (size_t)mrow * HW + n0 + tx4;
    if constexpr (sizeof(T) == 4) {
      *(float4*)op = make_float4(acc[i][0], acc[i][1], acc[i][2], acc[i][3]);
    } else {
#pragma unroll
      for (int j = 0; j < 4; ++j) stf(op + j, acc[i][j]);
    }
  }
}

// ---------------- Scan ----------------
// Grid (16, 64): blockIdx.y = batch, blockIdx.x = row-block (32 rows).
// 256 threads: g = tid&7 (row group of 4), ch = tid>>3 (col chunk of 16).
// Each thread: memreg[64] = 4 rows x 16 cols, held in VGPRs.
template <typename T>
__global__ __launch_bounds__(256, 4) void scan_kernel(const T* __restrict__ If,
                                                      float* __restrict__ mem_out,
                                                      float* __restrict__ keys,
                                                      float* __restrict__ vals) {
  const int b = blockIdx.y;
  const int rb = blockIdx.x;
  const int tid = threadIdx.x;
  const int g = tid & 7;     // row group
  const int ch = tid >> 3;   // col chunk 0..31
  const int r0 = rb << 5;    // first row of block

  __shared__ float k_s[2][640];    // swizzled, double-buffered
  __shared__ float kt_s[2][640];
  __shared__ float red_s[32][33];  // [chunk][row]
  __shared__ float red2_s[8][33];  // [seg][row]
  __shared__ __align__(16) float a_s[32];
  __shared__ __align__(16) float c_s[32];

  constexpr float ALPHA = 0.90483741803595957f;  // exp(-1/10)
  constexpr float DT    = 0.95122942450071400f;  // exp(-1/20)
  constexpr float OMD   = 0.04877057549928599f;  // 1 - DT
  constexpr float LR_   = 0.01f;

  float memreg[64];  // [i*16 + j]: row g*4+i, col ch*16+j
#pragma unroll
  for (int j = 0; j < 64; ++j) memreg[j] = 0.0f;
  float ks0 = 0.f, ks1 = 0.f, kt0 = 0.f, kt1 = 0.f, vs = 0.f, vt = 0.f;

  const T* ibase = If + (size_t)b * Sc * HW;
  float* keysb = keys + (size_t)b * Sc * Hh;
  float* valsb = vals + (size_t)b * Sc * Hh;

  const int h0 = 2 * tid;            // this thread's two k-chains
  const int sw0 = SWZ(h0);           // sw0+1 == SWZ(h0+1)
  const int row_red = tid & 31;      // reduction mapping
  const int seg_red = tid >> 5;

  for (int t = 0; t < Sc; ++t) {
    const T* row = ibase + (size_t)t * HW;
    const int buf = t & 1;

    // ---- phase 1: k-channel recurrence (512 chains, 2 per thread) ----
    float ik0, ik1;
    if constexpr (sizeof(T) == 4) {
      float2 v2 = *(const float2*)(row + h0);
      ik0 = v2.x; ik1 = v2.y;
    } else {
      __half2 hv = *(const __half2*)(row + h0);
      float2 v2 = __half22float2(hv);
      ik0 = v2.x; ik1 = v2.y;
    }
    float ivr = 0.0f;
    if (tid < 32) ivr = ldf(row + 512 + r0 + tid);

    ks0 = ALPHA * ks0 + ik0;
    ks1 = ALPHA * ks1 + ik1;
    float k0 = fast_tanh(ks0);
    float k1 = fast_tanh(ks1);
    kt0 = DT * kt0 + OMD * k0;
    kt1 = DT * kt1 + OMD * k1;
    k_s[buf][sw0] = k0;  k_s[buf][sw0 + 1] = k1;
    kt_s[buf][sw0] = kt0; kt_s[buf][sw0 + 1] = kt1;
    if (rb == 0) {
      *(float2*)&keysb[t * Hh + h0] = make_float2(k0, k1);
    }
    __syncthreads();  // B1

    // ---- phase 2: matvec partials over this thread's 4x16 patch ----
    {
      const float4* kc = (const float4*)&k_s[buf][ch * 20];
      float p0 = 0.f, p1 = 0.f, p2 = 0.f, p3 = 0.f;
#pragma unroll
      for (int q = 0; q < 4; ++q) {
        float4 kv = kc[q];
        const int o = q * 4;
        p0 += memreg[o+0]*kv.x + memreg[o+1]*kv.y + memreg[o+2]*kv.z + memreg[o+3]*kv.w;
        p1 += memreg[16+o+0]*kv.x + memreg[16+o+1]*kv.y + memreg[16+o+2]*kv.z + memreg[16+o+3]*kv.w;
        p2 += memreg[32+o+0]*kv.x + memreg[32+o+1]*kv.y + memreg[32+o+2]*kv.z + memreg[32+o+3]*kv.w;
        p3 += memreg[48+o+0]*kv.x + memreg[48+o+1]*kv.y + memreg[48+o+2]*kv.z + memreg[48+o+3]*kv.w;
      }
      const int rbase = g << 2;
      red_s[ch][rbase + 0] = p0;
      red_s[ch][rbase + 1] = p1;
      red_s[ch][rbase + 2] = p2;
      red_s[ch][rbase + 3] = p3;
    }
    __syncthreads();  // B2

    // ---- reduce 32 chunks -> 8 segments ----
    {
      const int c0 = seg_red << 2;
      float s = red_s[c0][row_red] + red_s[c0 + 1][row_red] +
                red_s[c0 + 2][row_red] + red_s[c0 + 3][row_red];
      red2_s[seg_red][row_red] = s;
    }
    __syncthreads();  // B2b

    // ---- phase 3: v-recurrence (one lane per row) ----
    if (tid < 32) {
      float ikv = 0.f;
#pragma unroll
      for (int s = 0; s < 8; ++s) ikv += red2_s[s][tid];
      ikv *= 0.2f;
      vs = ALPHA * vs + ivr + ikv;
      float v = fast_tanh(vs);
      vt = DT * vt + OMD * v;
      valsb[t * Hh + r0 + tid] = v;
      a_s[tid] = 1.0f - LR_ * vt * vt;
      c_s[tid] = LR_ * vt;
    }
    __syncthreads();  // B3

    // ---- phase 4: rank-1 mem update ----
    {
      float4 av = *(const float4*)&a_s[g << 2];
      float4 cv = *(const float4*)&c_s[g << 2];
      const float4* kt4 = (const float4*)&kt_s[buf][ch * 20];
#pragma unroll
      for (int q = 0; q < 4; ++q) {
        float4 kv = kt4[q];
        const int o = q * 4;
        memreg[o+0]    = fmaf(memreg[o+0],    av.x, cv.x * kv.x);
        memreg[o+1]    = fmaf(memreg[o+1],    av.x, cv.x * kv.y);
        memreg[o+2]    = fmaf(memreg[o+2],    av.x, cv.x * kv.z);
        memreg[o+3]    = fmaf(memreg[o+3],    av.x, cv.x * kv.w);
        memreg[16+o+0] = fmaf(memreg[16+o+0], av.y, cv.y * kv.x);
        memreg[16+o+1] = fmaf(memreg[16+o+1], av.y, cv.y * kv.y);
        memreg[16+o+2] = fmaf(memreg[16+o+2], av.y, cv.y * kv.z);
        memreg[16+o+3] = fmaf(memreg[16+o+3], av.y, cv.y * kv.w);
        memreg[32+o+0] = fmaf(memreg[32+o+0], av.z, cv.z * kv.x);
        memreg[32+o+1] = fmaf(memreg[32+o+1], av.z, cv.z * kv.y);
        memreg[32+o+2] = fmaf(memreg[32+o+2], av.z, cv.z * kv.z);
        memreg[32+o+3] = fmaf(memreg[32+o+3], av.z, cv.z * kv.w);
        memreg[48+o+0] = fmaf(memreg[48+o+0], av.w, cv.w * kv.x);
        memreg[48+o+1] = fmaf(memreg[48+o+1], av.w, cv.w * kv.y);
        memreg[48+o+2] = fmaf(memreg[48+o+2], av.w, cv.w * kv.z);
        memreg[48+o+3] = fmaf(memreg[48+o+3], av.w, cv.w * kv.w);
      }
    }
    // no barrier: next step's phase1 writes the other k_s buffer; B1 covers.
  }

  // epilogue: write mem (once)
#pragma unroll
  for (int i = 0; i < 4; ++i) {
    float* mb = mem_out + (size_t)b * Hh * Hh +
                (size_t)(r0 + (g << 2) + i) * Hh + (ch << 4);
#pragma unroll
    for (int q = 0; q < 4; ++q) {
      *(float4*)(mb + 4 * q) = make_float4(memreg[i*16 + 4*q + 0], memreg[i*16 + 4*q + 1],
                                           memreg[i*16 + 4*q + 2], memreg[i*16 + 4*q + 3]);
    }
  }
}

extern "C" void kernel_launch(void* const* d_in, const int* in_sizes, int n_in,
                              void* d_out, int out_size, void* d_ws, size_t ws_size,
                              hipStream_t stream) {
  const float* x = (const float*)d_in[0];   // (64,256,256) fp32
  const float* W = (const float*)d_in[1];   // (1024,256) fp32
  float* out = (float*)d_out;
  float* mem_out = out;                          // 16,777,216 floats
  float* keys    = out + 16777216;               //  8,388,608 floats
  float* vals    = out + 25165824;               //  8,388,608 floats

  const dim3 gemm_grid(128, 16), gemm_blk(256);
  const dim3 scan_grid(16, 64),  scan_blk(256);
  const size_t i_elems = (size_t)Bc * Sc * HW;   // 16,777,216

  if (ws_size >= i_elems * sizeof(float)) {
    float* If = (float*)d_ws;
    gemm_xw<float><<<gemm_grid, gemm_blk, 0, stream>>>(x, W, If);
    scan_kernel<float><<<scan_grid, scan_blk, 0, stream>>>(If, mem_out, keys, vals);
  } else {
    __half* If = (__half*)d_ws;
    gemm_xw<__half><<<gemm_grid, gemm_blk, 0, stream>>>(x, W, If);
    scan_kernel<__half><<<scan_grid, scan_blk, 0, stream>>>(If, mem_out, keys, vals);
  }
}